// Round 2
// baseline (40.249 us; speedup 1.0000x reference)
//
#include <hip/hip_runtime.h>

// GraphSAGE encoder forward, fused single kernel (v2).
// Inputs (setup_inputs order):
//  d_in[0] emb       f32 [1M, 128]
//  d_in[1] neigh_w   f32 [8192, 10]
//  d_in[2] W         f32 [256, 128]
//  d_in[3] b         f32 [128]
//  d_in[4] nodes     i32 [8192]
//  d_in[5] neigh_ids i32 [8192, 10]
// Output: f32 [8192, 128]  = swish(concat(self, weighted-mean-neigh) @ W + b)
//
// v2 changes vs v1 (25.76 us):
//  - NPB 16 -> 8: 1024 blocks = 4 blocks/CU (was 2) for cross-block
//    phase overlap + latency hiding.
//  - Phase 1: float4 gathers, half-wave per node -> 1 load instr per
//    512B emb row, 11 independent row loads in flight per wave.
//  - Phase 2: each thread owns 4 consecutive output cols -> W reads are
//    coalesced float4 (256 load instrs per 1024 FMAs, was 768/2048).

#define B_NODES 8192
#define K_NEIGH 10
#define FDIM 128
#define EDIM 128
#define NPB 8            // nodes per block
#define THREADS 256

__global__ __launch_bounds__(THREADS) void sage_fused(
    const float* __restrict__ emb,
    const float* __restrict__ neigh_w,
    const float* __restrict__ Wm,
    const float* __restrict__ bias,
    const int*   __restrict__ nodes,
    const int*   __restrict__ neigh_ids,
    float* __restrict__ out)
{
    __shared__ __align__(16) float Xs[NPB][2 * FDIM];   // 8 x 256 f32 = 8 KB

    const int tid  = threadIdx.x;
    const int nb0  = blockIdx.x * NPB;

    // ---------------- Phase 1: gather + weighted aggregate into LDS ----------
    // half-wave (32 lanes) per node: lane covers float4 of the 128-dim row.
    {
        const int half = tid >> 5;            // 0..7 == local node index
        const int l32  = tid & 31;
        const int d0   = l32 * 4;
        const int nb   = nb0 + half;

        // neighbor ids + self id first: get loads in flight early
        int ids[K_NEIGH];
        #pragma unroll
        for (int k = 0; k < K_NEIGH; ++k) ids[k] = neigh_ids[nb * K_NEIGH + k];
        const int sid = nodes[nb];

        float wk[K_NEIGH];
        float wsum = 0.f;
        #pragma unroll
        for (int k = 0; k < K_NEIGH; ++k) {
            wk[k] = neigh_w[nb * K_NEIGH + k];
            wsum += wk[k];
        }
        const float inv = 1.f / wsum;

        const float4 sv = *reinterpret_cast<const float4*>(&emb[sid * FDIM + d0]);

        float4 a = make_float4(0.f, 0.f, 0.f, 0.f);
        #pragma unroll
        for (int k = 0; k < K_NEIGH; ++k) {
            const float4 v = *reinterpret_cast<const float4*>(&emb[ids[k] * FDIM + d0]);
            a.x = fmaf(wk[k], v.x, a.x);
            a.y = fmaf(wk[k], v.y, a.y);
            a.z = fmaf(wk[k], v.z, a.z);
            a.w = fmaf(wk[k], v.w, a.w);
        }

        *reinterpret_cast<float4*>(&Xs[half][d0]) = sv;
        *reinterpret_cast<float4*>(&Xs[half][FDIM + d0]) =
            make_float4(a.x * inv, a.y * inv, a.z * inv, a.w * inv);
    }
    __syncthreads();

    // ---------------- Phase 2: [8 x 256] @ W[256 x 128] + b, swish -----------
    // thread -> row g = tid>>5 (0..7), cols c0..c0+3 (c0 = (tid&31)*4).
    // X via LDS broadcast (uniform per half-wave); W coalesced float4.
    {
        const int g  = tid >> 5;
        const int c0 = (tid & 31) * 4;

        float4 acc = *reinterpret_cast<const float4*>(&bias[c0]);

        #pragma unroll 4
        for (int d = 0; d < 2 * FDIM; d += 4) {
            const float4 xv = *reinterpret_cast<const float4*>(&Xs[g][d]);
            const float4 w0 = *reinterpret_cast<const float4*>(&Wm[(d + 0) * EDIM + c0]);
            const float4 w1 = *reinterpret_cast<const float4*>(&Wm[(d + 1) * EDIM + c0]);
            const float4 w2 = *reinterpret_cast<const float4*>(&Wm[(d + 2) * EDIM + c0]);
            const float4 w3 = *reinterpret_cast<const float4*>(&Wm[(d + 3) * EDIM + c0]);

            acc.x = fmaf(xv.x, w0.x, acc.x); acc.y = fmaf(xv.x, w0.y, acc.y);
            acc.z = fmaf(xv.x, w0.z, acc.z); acc.w = fmaf(xv.x, w0.w, acc.w);
            acc.x = fmaf(xv.y, w1.x, acc.x); acc.y = fmaf(xv.y, w1.y, acc.y);
            acc.z = fmaf(xv.y, w1.z, acc.z); acc.w = fmaf(xv.y, w1.w, acc.w);
            acc.x = fmaf(xv.z, w2.x, acc.x); acc.y = fmaf(xv.z, w2.y, acc.y);
            acc.z = fmaf(xv.z, w2.z, acc.z); acc.w = fmaf(xv.z, w2.w, acc.w);
            acc.x = fmaf(xv.w, w3.x, acc.x); acc.y = fmaf(xv.w, w3.y, acc.y);
            acc.z = fmaf(xv.w, w3.z, acc.z); acc.w = fmaf(xv.w, w3.w, acc.w);
        }

        const int row = nb0 + g;
        float4 o;
        o.x = acc.x / (1.f + __expf(-acc.x));
        o.y = acc.y / (1.f + __expf(-acc.y));
        o.z = acc.z / (1.f + __expf(-acc.z));
        o.w = acc.w / (1.f + __expf(-acc.w));
        *reinterpret_cast<float4*>(&out[row * EDIM + c0]) = o;
    }
}

extern "C" void kernel_launch(void* const* d_in, const int* in_sizes, int n_in,
                              void* d_out, int out_size, void* d_ws, size_t ws_size,
                              hipStream_t stream) {
    const float* emb       = (const float*)d_in[0];
    const float* neigh_w   = (const float*)d_in[1];
    const float* Wm        = (const float*)d_in[2];
    const float* bias      = (const float*)d_in[3];
    const int*   nodes     = (const int*)d_in[4];
    const int*   neigh_ids = (const int*)d_in[5];
    float* out = (float*)d_out;

    const int blocks = B_NODES / NPB;   // 1024 -> 4 blocks/CU
    sage_fused<<<dim3(blocks), dim3(THREADS), 0, stream>>>(
        emb, neigh_w, Wm, bias, nodes, neigh_ids, out);
}

// Round 3
// 33.061 us; speedup vs baseline: 1.2174x; 1.2174x over previous
//
#include <hip/hip_runtime.h>

// GraphSAGE encoder forward, fused single kernel (v3).
//  v1 (25.76us): serial gather -> sync -> GEMM, scalar-W coalesced, 512 blocks.
//  v2 (40.25us, REGRESSION): float4 W reads duplicated per row-group ->
//     ~1 GB L2 traffic (~29us at 34.5 TB/s). Reverted.
//  v3: K-split GEMM (W read once per block-half, LDS reduce) + software
//     pipelining: half1 gather loads in flight under half0's GEMM FMAs.
//
// Inputs: emb f32[1M,128], neigh_w f32[8192,10], W f32[256,128], b f32[128],
//         nodes i32[8192], neigh_ids i32[8192,10]. Out f32[8192,128].

#define B_NODES 8192
#define K_NEIGH 10
#define FDIM 128
#define EDIM 128
#define NPB 16
#define HALF 8
#define THREADS 256

__device__ __forceinline__ void gemm_half(
    const float (*Xs)[2 * FDIM], int rbase, const float* __restrict__ Wm,
    int h, int e, float* acc)
{
#pragma unroll
    for (int r = 0; r < HALF; ++r) acc[r] = 0.f;
    const float* Wp = Wm + (size_t)(h * FDIM) * EDIM + e;
#pragma unroll 2
    for (int d = 0; d < FDIM; d += 4) {
        // scalar W loads: coalesced across lanes (lane -> e), 4B/lane.
        const float w0 = Wp[(d + 0) * EDIM];
        const float w1 = Wp[(d + 1) * EDIM];
        const float w2 = Wp[(d + 2) * EDIM];
        const float w3 = Wp[(d + 3) * EDIM];
#pragma unroll
        for (int r = 0; r < HALF; ++r) {
            // wave-uniform address -> LDS broadcast, conflict-free
            const float4 xv = *reinterpret_cast<const float4*>(&Xs[rbase + r][h * FDIM + d]);
            acc[r] = fmaf(xv.x, w0, fmaf(xv.y, w1, fmaf(xv.z, w2, fmaf(xv.w, w3, acc[r]))));
        }
    }
}

__global__ __launch_bounds__(THREADS, 2) void sage_fused(
    const float* __restrict__ emb,
    const float* __restrict__ neigh_w,
    const float* __restrict__ Wm,
    const float* __restrict__ bias,
    const int*   __restrict__ nodes,
    const int*   __restrict__ neigh_ids,
    float* __restrict__ out)
{
    __shared__ __align__(16) float Xs[NPB][2 * FDIM];   // 16 KB
    __shared__ float redA[HALF][EDIM];                  // 4 KB
    __shared__ float redB[HALF][EDIM];                  // 4 KB
    __shared__ int   s_ids[NPB * K_NEIGH];
    __shared__ float s_w[NPB * K_NEIGH];
    __shared__ int   s_self[NPB];

    const int tid  = threadIdx.x;
    const int wave = tid >> 6;
    const int lane = tid & 63;
    const int d0   = lane * 2;          // gather: lane covers 2 dims (512B/wave)
    const int nb0  = blockIdx.x * NPB;

    const int e = tid & (EDIM - 1);     // GEMM: output column
    const int h = tid >> 7;             // GEMM: K-half
    const float bv = bias[e];

    // ---- Stage A: metadata to LDS (coalesced, once per block) --------------
    if (tid < NPB) s_self[tid] = nodes[nb0 + tid];
    if (tid < NPB * K_NEIGH) {
        s_ids[tid] = neigh_ids[nb0 * K_NEIGH + tid];
        s_w[tid]   = neigh_w[nb0 * K_NEIGH + tid];
    }
    __syncthreads();    // S0

    // ---- B0: gather half 0 (wave handles nodes 2w, 2w+1) -------------------
    {
        const int nA = wave * 2, nB = nA + 1;
        const float2 sA = *reinterpret_cast<const float2*>(&emb[(size_t)s_self[nA] * FDIM + d0]);
        const float2 sB = *reinterpret_cast<const float2*>(&emb[(size_t)s_self[nB] * FDIM + d0]);
        float2 vA[K_NEIGH], vB[K_NEIGH];
#pragma unroll
        for (int k = 0; k < K_NEIGH; ++k)
            vA[k] = *reinterpret_cast<const float2*>(&emb[(size_t)s_ids[nA * K_NEIGH + k] * FDIM + d0]);
#pragma unroll
        for (int k = 0; k < K_NEIGH; ++k)
            vB[k] = *reinterpret_cast<const float2*>(&emb[(size_t)s_ids[nB * K_NEIGH + k] * FDIM + d0]);

        float wA[K_NEIGH], wB[K_NEIGH], wsA = 0.f, wsB = 0.f;
#pragma unroll
        for (int k = 0; k < K_NEIGH; ++k) { wA[k] = s_w[nA * K_NEIGH + k]; wsA += wA[k]; }
#pragma unroll
        for (int k = 0; k < K_NEIGH; ++k) { wB[k] = s_w[nB * K_NEIGH + k]; wsB += wB[k]; }
        const float invA = 1.f / wsA, invB = 1.f / wsB;

        float ax = 0.f, ay = 0.f, bx = 0.f, by = 0.f;
#pragma unroll
        for (int k = 0; k < K_NEIGH; ++k) {
            ax = fmaf(wA[k], vA[k].x, ax); ay = fmaf(wA[k], vA[k].y, ay);
            bx = fmaf(wB[k], vB[k].x, bx); by = fmaf(wB[k], vB[k].y, by);
        }
        Xs[nA][d0] = sA.x; Xs[nA][d0 + 1] = sA.y;
        Xs[nB][d0] = sB.x; Xs[nB][d0 + 1] = sB.y;
        Xs[nA][FDIM + d0] = ax * invA; Xs[nA][FDIM + d0 + 1] = ay * invA;
        Xs[nB][FDIM + d0] = bx * invB; Xs[nB][FDIM + d0 + 1] = by * invB;
    }
    __syncthreads();    // S1: Xs[0..7] ready

    // ---- B1-issue: half-1 gather loads go in flight NOW ---------------------
    const int nA = HALF + wave * 2, nB = nA + 1;
    const float2 sA = *reinterpret_cast<const float2*>(&emb[(size_t)s_self[nA] * FDIM + d0]);
    const float2 sB = *reinterpret_cast<const float2*>(&emb[(size_t)s_self[nB] * FDIM + d0]);
    float2 vA[K_NEIGH], vB[K_NEIGH];
#pragma unroll
    for (int k = 0; k < K_NEIGH; ++k)
        vA[k] = *reinterpret_cast<const float2*>(&emb[(size_t)s_ids[nA * K_NEIGH + k] * FDIM + d0]);
#pragma unroll
    for (int k = 0; k < K_NEIGH; ++k)
        vB[k] = *reinterpret_cast<const float2*>(&emb[(size_t)s_ids[nB * K_NEIGH + k] * FDIM + d0]);

    // ---- C0-fma: GEMM half 0 (hides half-1 gather latency) ------------------
    float acc0[HALF];
    gemm_half(Xs, 0, Wm, h, e, acc0);

    // ---- B1-finish: accumulate + write Xs[8..15] ----------------------------
    {
        float wA[K_NEIGH], wB[K_NEIGH], wsA = 0.f, wsB = 0.f;
#pragma unroll
        for (int k = 0; k < K_NEIGH; ++k) { wA[k] = s_w[nA * K_NEIGH + k]; wsA += wA[k]; }
#pragma unroll
        for (int k = 0; k < K_NEIGH; ++k) { wB[k] = s_w[nB * K_NEIGH + k]; wsB += wB[k]; }
        const float invA = 1.f / wsA, invB = 1.f / wsB;
        float ax = 0.f, ay = 0.f, bx = 0.f, by = 0.f;
#pragma unroll
        for (int k = 0; k < K_NEIGH; ++k) {
            ax = fmaf(wA[k], vA[k].x, ax); ay = fmaf(wA[k], vA[k].y, ay);
            bx = fmaf(wB[k], vB[k].x, bx); by = fmaf(wB[k], vB[k].y, by);
        }
        Xs[nA][d0] = sA.x; Xs[nA][d0 + 1] = sA.y;
        Xs[nB][d0] = sB.x; Xs[nB][d0 + 1] = sB.y;
        Xs[nA][FDIM + d0] = ax * invA; Xs[nA][FDIM + d0 + 1] = ay * invA;
        Xs[nB][FDIM + d0] = bx * invB; Xs[nB][FDIM + d0 + 1] = by * invB;
    }
    if (h == 1) {
#pragma unroll
        for (int r = 0; r < HALF; ++r) redA[r][e] = acc0[r];
    }
    __syncthreads();    // S2: Xs[8..15] + redA ready

    // ---- finalize half 0 (h==0 waves) ; h==1 waves fall through to C1 -------
    if (h == 0) {
#pragma unroll
        for (int r = 0; r < HALF; ++r) {
            const float v = acc0[r] + redA[r][e] + bv;
            out[(size_t)(nb0 + r) * EDIM + e] = v / (1.f + __expf(-v));
        }
    }

    // ---- C1-fma: GEMM half 1 ------------------------------------------------
    float acc1[HALF];
    gemm_half(Xs, HALF, Wm, h, e, acc1);

    if (h == 1) {
#pragma unroll
        for (int r = 0; r < HALF; ++r) redB[r][e] = acc1[r];
    }
    __syncthreads();    // S3

    if (h == 0) {
#pragma unroll
        for (int r = 0; r < HALF; ++r) {
            const float v = acc1[r] + redB[r][e] + bv;
            out[(size_t)(nb0 + HALF + r) * EDIM + e] = v / (1.f + __expf(-v));
        }
    }
}

extern "C" void kernel_launch(void* const* d_in, const int* in_sizes, int n_in,
                              void* d_out, int out_size, void* d_ws, size_t ws_size,
                              hipStream_t stream) {
    const float* emb       = (const float*)d_in[0];
    const float* neigh_w   = (const float*)d_in[1];
    const float* Wm        = (const float*)d_in[2];
    const float* bias      = (const float*)d_in[3];
    const int*   nodes     = (const int*)d_in[4];
    const int*   neigh_ids = (const int*)d_in[5];
    float* out = (float*)d_out;

    const int blocks = B_NODES / NPB;   // 512
    sage_fused<<<dim3(blocks), dim3(THREADS), 0, stream>>>(
        emb, neigh_w, Wm, bias, nodes, neigh_ids, out);
}